// Round 1
// baseline (470.874 us; speedup 1.0000x reference)
//
#include <hip/hip_runtime.h>
#include <math.h>

#define EPS 1e-6f

// ---------------- Kernel 1: per-(b,c) spatial mean of x (64x64 = 4096) -------
__global__ __launch_bounds__(256) void mean_kernel(const float* __restrict__ x,
                                                   float* __restrict__ y) {
    int plane = blockIdx.x;  // b*512 + c, 8192 planes
    const float4* xp = (const float4*)(x + (size_t)plane * 4096);
    int t = threadIdx.x;
    float sum = 0.f;
#pragma unroll
    for (int k = 0; k < 4; ++k) {
        float4 v = xp[t + k * 256];
        sum += v.x + v.y + v.z + v.w;
    }
    // wave64 shuffle reduce
#pragma unroll
    for (int off = 32; off > 0; off >>= 1)
        sum += __shfl_down(sum, off, 64);
    __shared__ float lds[4];
    if ((t & 63) == 0) lds[t >> 6] = sum;
    __syncthreads();
    if (t == 0) {
        float s = lds[0] + lds[1] + lds[2] + lds[3];
        y[plane] = s * (1.0f / 4096.0f);
    }
}

// ---------------- Kernel 2: channel conv1d (k=5, SAME) + elu+1 + z_new -------
__global__ __launch_bounds__(256) void qk_kernel(const float* __restrict__ y,
                                                 const float* __restrict__ z,
                                                 const float* __restrict__ wq,
                                                 const float* __restrict__ wk,
                                                 float* __restrict__ kf_out,
                                                 float* __restrict__ factor_out,
                                                 float* __restrict__ znew_out) {
    int gid = blockIdx.x * blockDim.x + threadIdx.x;  // 0..8191
    int b = gid >> 9;
    int ch = gid & 511;
    float q = 0.f, k = 0.f;
#pragma unroll
    for (int i = 0; i < 5; ++i) {
        int cc = ch + i - 2;
        float yv = (cc >= 0 && cc < 512) ? y[b * 512 + cc] : 0.f;
        q += yv * wq[i];
        k += yv * wk[i];
    }
    float qf = (q > 0.f) ? (q + 1.f) : expf(q);  // elu(q)+1
    float kf = (k > 0.f) ? (k + 1.f) : expf(k);  // elu(k)+1
    float zn = z[gid] + kf;
    znew_out[gid] = zn;
    float qz = 1.0f / (qf * (zn + EPS));
    kf_out[gid] = kf;
    factor_out[gid] = qf * qz;  // matches numpy op order
}

// ------- Kernel 3: fused depthwise 3x3 conv + s_new + out (the big one) ------
// Block: 256 threads = 16 rows x (16 threads x 4 px). 4 blocks per (b,c) plane.
__global__ __launch_bounds__(256) void fused_kernel(
    const float* __restrict__ x, const float* __restrict__ s,
    const float* __restrict__ wv, const float* __restrict__ kf_arr,
    const float* __restrict__ factor_arr, float* __restrict__ out,
    float* __restrict__ s_new) {
    int plane = blockIdx.x >> 2;   // b*512 + c
    int chunk = blockIdx.x & 3;    // which 16-row band
    int ch = plane & 511;
    float kf = kf_arr[plane];
    float fac = factor_arr[plane];
    const float* wvp = wv + ch * 9;
    float w00 = wvp[0], w01 = wvp[1], w02 = wvp[2];
    float w10 = wvp[3], w11 = wvp[4], w12 = wvp[5];
    float w20 = wvp[6], w21 = wvp[7], w22 = wvp[8];

    int ty = threadIdx.x >> 4;   // 0..15
    int tx = threadIdx.x & 15;   // 0..15
    int row = chunk * 16 + ty;   // 0..63
    int col0 = tx << 2;          // 0,4,...,60

    const float* xp = x + (size_t)plane * 4096;

    float r0[6], r1[6], r2[6];
    // load a row's 6-wide window [col0-1, col0+4] with zero padding
    {
        const int rows[3] = {row - 1, row, row + 1};
        float* bufs[3] = {r0, r1, r2};
#pragma unroll
        for (int rr = 0; rr < 3; ++rr) {
            int r = rows[rr];
            float* buf = bufs[rr];
            if (r < 0 || r >= 64) {
#pragma unroll
                for (int m = 0; m < 6; ++m) buf[m] = 0.f;
            } else {
                const float* rp = xp + r * 64 + col0;
                buf[0] = (col0 == 0) ? 0.f : rp[-1];
                float4 v = *(const float4*)rp;  // 16B aligned
                buf[1] = v.x;
                buf[2] = v.y;
                buf[3] = v.z;
                buf[4] = v.w;
                buf[5] = (col0 + 4 >= 64) ? 0.f : rp[4];
            }
        }
    }

    float vj[4];
#pragma unroll
    for (int j = 0; j < 4; ++j) {
        vj[j] = r0[j] * w00 + r0[j + 1] * w01 + r0[j + 2] * w02 +
                r1[j] * w10 + r1[j + 1] * w11 + r1[j + 2] * w12 +
                r2[j] * w20 + r2[j + 1] * w21 + r2[j + 2] * w22;
    }

    size_t off = (size_t)plane * 4096 + (size_t)row * 64 + col0;
    float4 s4 = *(const float4*)(s + off);
    float4 sn;
    sn.x = s4.x + kf * vj[0];
    sn.y = s4.y + kf * vj[1];
    sn.z = s4.z + kf * vj[2];
    sn.w = s4.w + kf * vj[3];
    *(float4*)(s_new + off) = sn;
    float4 o;
    o.x = fac * sn.x;
    o.y = fac * sn.y;
    o.z = fac * sn.z;
    o.w = fac * sn.w;
    *(float4*)(out + off) = o;
}

extern "C" void kernel_launch(void* const* d_in, const int* in_sizes, int n_in,
                              void* d_out, int out_size, void* d_ws,
                              size_t ws_size, hipStream_t stream) {
    const float* x  = (const float*)d_in[0];  // [16,512,64,64]
    const float* s  = (const float*)d_in[1];  // [16,512,1,4096]
    const float* z  = (const float*)d_in[2];  // [16,1,512,1]
    const float* wq = (const float*)d_in[3];  // [1,1,5]
    const float* wk = (const float*)d_in[4];  // [1,1,5]
    const float* wv = (const float*)d_in[5];  // [512,1,3,3]

    float* out   = (float*)d_out;            // [16,512,64,64] = 33554432
    float* s_new = out + 33554432;           // [16,512,1,4096] = 33554432
    float* z_new = s_new + 33554432;         // [16,1,512,1] = 8192

    float* ws     = (float*)d_ws;
    float* y      = ws;          // 8192 floats
    float* kf     = ws + 8192;   // 8192 floats
    float* factor = ws + 16384;  // 8192 floats

    mean_kernel<<<8192, 256, 0, stream>>>(x, y);
    qk_kernel<<<32, 256, 0, stream>>>(y, z, wq, wk, kf, factor, z_new);
    fused_kernel<<<32768, 256, 0, stream>>>(x, s, wv, kf, factor, out, s_new);
}

// Round 2
// 454.826 us; speedup vs baseline: 1.0353x; 1.0353x over previous
//
#include <hip/hip_runtime.h>
#include <math.h>

#define EPS 1e-6f

// ---------------- Kernel 1: per-(b,c) spatial mean of x (64x64 = 4096) -------
__global__ __launch_bounds__(256) void mean_kernel(const float* __restrict__ x,
                                                   float* __restrict__ y) {
    int plane = blockIdx.x;  // b*512 + c, 8192 planes
    const float4* xp = (const float4*)(x + (size_t)plane * 4096);
    int t = threadIdx.x;
    float sum = 0.f;
#pragma unroll
    for (int k = 0; k < 4; ++k) {
        float4 v = xp[t + k * 256];
        sum += v.x + v.y + v.z + v.w;
    }
    // wave64 shuffle reduce
#pragma unroll
    for (int off = 32; off > 0; off >>= 1)
        sum += __shfl_down(sum, off, 64);
    __shared__ float lds[4];
    if ((t & 63) == 0) lds[t >> 6] = sum;
    __syncthreads();
    if (t == 0) {
        float s = lds[0] + lds[1] + lds[2] + lds[3];
        y[plane] = s * (1.0f / 4096.0f);
    }
}

// ---------------- Kernel 2: channel conv1d (k=5, SAME) + elu+1 + z_new -------
__global__ __launch_bounds__(256) void qk_kernel(const float* __restrict__ y,
                                                 const float* __restrict__ z,
                                                 const float* __restrict__ wq,
                                                 const float* __restrict__ wk,
                                                 float* __restrict__ kf_out,
                                                 float* __restrict__ factor_out,
                                                 float* __restrict__ znew_out) {
    int gid = blockIdx.x * blockDim.x + threadIdx.x;  // 0..8191
    int b = gid >> 9;
    int ch = gid & 511;
    float q = 0.f, k = 0.f;
#pragma unroll
    for (int i = 0; i < 5; ++i) {
        int cc = ch + i - 2;
        float yv = (cc >= 0 && cc < 512) ? y[b * 512 + cc] : 0.f;
        q += yv * wq[i];
        k += yv * wk[i];
    }
    float qf = (q > 0.f) ? (q + 1.f) : expf(q);  // elu(q)+1
    float kf = (k > 0.f) ? (k + 1.f) : expf(k);  // elu(k)+1
    float zn = z[gid] + kf;
    znew_out[gid] = zn;
    float qz = 1.0f / (qf * (zn + EPS));
    kf_out[gid] = kf;
    factor_out[gid] = qf * qz;  // matches numpy op order
}

// ------- Kernel 3: fused depthwise 3x3 conv + s_new + out (the big one) ------
// One block per (b,c) plane. Stage 64x64 plane in LDS (16 KB), then each
// thread computes 4 rows x 4 cols from LDS. No scratch arrays, no scalar
// global loads -- all global traffic is float4-coalesced.
__global__ __launch_bounds__(256) void fused_kernel(
    const float* __restrict__ x, const float* __restrict__ s,
    const float* __restrict__ wv, const float* __restrict__ kf_arr,
    const float* __restrict__ factor_arr, float* __restrict__ out,
    float* __restrict__ s_new) {
    __shared__ float tile[4096];

    int plane = blockIdx.x;      // b*512 + c
    int ch = plane & 511;
    float kf = kf_arr[plane];
    float fac = factor_arr[plane];
    const float* wvp = wv + ch * 9;
    float w00 = wvp[0], w01 = wvp[1], w02 = wvp[2];
    float w10 = wvp[3], w11 = wvp[4], w12 = wvp[5];
    float w20 = wvp[6], w21 = wvp[7], w22 = wvp[8];

    int t = threadIdx.x;
    const float4* xp4 = (const float4*)(x + (size_t)plane * 4096);
    float4* t4 = (float4*)tile;
#pragma unroll
    for (int k = 0; k < 4; ++k)
        t4[t + k * 256] = xp4[t + k * 256];
    __syncthreads();

    int ty = t >> 4;             // 0..15
    int tx = t & 15;             // 0..15
    int col0 = tx << 2;          // 0,4,...,60

    // column-edge masks (same for every row this thread touches)
    float lm = (col0 == 0) ? 0.f : 1.f;
    float rm = (col0 == 60) ? 0.f : 1.f;
    int li = (col0 == 0) ? 0 : col0 - 1;     // clamped left index
    int ri = (col0 == 60) ? 63 : col0 + 4;   // clamped right index

#pragma unroll
    for (int rr = 0; rr < 4; ++rr) {
        int row = ty + rr * 16;  // 0..63
        int rcB = row * 64;
        int rmB = (row == 0) ? rcB : rcB - 64;
        int rpB = (row == 63) ? rcB : rcB + 64;
        float tm = (row == 0) ? 0.f : 1.f;
        float bm = (row == 63) ? 0.f : 1.f;

        float4 tq = *(const float4*)(tile + rmB + col0);
        float t0 = tile[rmB + li] * (tm * lm);
        float t1 = tq.x * tm, t2 = tq.y * tm, t3 = tq.z * tm, t4v = tq.w * tm;
        float t5 = tile[rmB + ri] * (tm * rm);

        float4 cq = *(const float4*)(tile + rcB + col0);
        float c0 = tile[rcB + li] * lm;
        float c1 = cq.x, c2 = cq.y, c3 = cq.z, c4 = cq.w;
        float c5 = tile[rcB + ri] * rm;

        float4 bq = *(const float4*)(tile + rpB + col0);
        float b0 = tile[rpB + li] * (bm * lm);
        float b1 = bq.x * bm, b2 = bq.y * bm, b3 = bq.z * bm, b4 = bq.w * bm;
        float b5 = tile[rpB + ri] * (bm * rm);

        float v0 = t0 * w00 + t1 * w01 + t2 * w02 +
                   c0 * w10 + c1 * w11 + c2 * w12 +
                   b0 * w20 + b1 * w21 + b2 * w22;
        float v1 = t1 * w00 + t2 * w01 + t3 * w02 +
                   c1 * w10 + c2 * w11 + c3 * w12 +
                   b1 * w20 + b2 * w21 + b3 * w22;
        float v2 = t2 * w00 + t3 * w01 + t4v * w02 +
                   c2 * w10 + c3 * w11 + c4 * w12 +
                   b2 * w20 + b3 * w21 + b4 * w22;
        float v3 = t3 * w00 + t4v * w01 + t5 * w02 +
                   c3 * w10 + c4 * w11 + c5 * w12 +
                   b3 * w20 + b4 * w21 + b5 * w22;

        size_t off = (size_t)plane * 4096 + (size_t)rcB + col0;
        float4 s4 = *(const float4*)(s + off);
        float4 sn;
        sn.x = s4.x + kf * v0;
        sn.y = s4.y + kf * v1;
        sn.z = s4.z + kf * v2;
        sn.w = s4.w + kf * v3;
        *(float4*)(s_new + off) = sn;
        float4 o;
        o.x = fac * sn.x;
        o.y = fac * sn.y;
        o.z = fac * sn.z;
        o.w = fac * sn.w;
        *(float4*)(out + off) = o;
    }
}

extern "C" void kernel_launch(void* const* d_in, const int* in_sizes, int n_in,
                              void* d_out, int out_size, void* d_ws,
                              size_t ws_size, hipStream_t stream) {
    const float* x  = (const float*)d_in[0];  // [16,512,64,64]
    const float* s  = (const float*)d_in[1];  // [16,512,1,4096]
    const float* z  = (const float*)d_in[2];  // [16,1,512,1]
    const float* wq = (const float*)d_in[3];  // [1,1,5]
    const float* wk = (const float*)d_in[4];  // [1,1,5]
    const float* wv = (const float*)d_in[5];  // [512,1,3,3]

    float* out   = (float*)d_out;            // [16,512,64,64] = 33554432
    float* s_new = out + 33554432;           // [16,512,1,4096] = 33554432
    float* z_new = s_new + 33554432;         // [16,1,512,1] = 8192

    float* ws     = (float*)d_ws;
    float* y      = ws;          // 8192 floats
    float* kf     = ws + 8192;   // 8192 floats
    float* factor = ws + 16384;  // 8192 floats

    mean_kernel<<<8192, 256, 0, stream>>>(x, y);
    qk_kernel<<<32, 256, 0, stream>>>(y, z, wq, wk, kf, factor, z_new);
    fused_kernel<<<8192, 256, 0, stream>>>(x, s, wv, kf, factor, out, s_new);
}